// Round 1
// baseline (1885.830 us; speedup 1.0000x reference)
//
#include <hip/hip_runtime.h>
#include <hip/hip_bf16.h>
#include <cstdint>

// ---------------------------------------------------------------------------
// GRU-D: B=256, T=512, D=128, H=256.
// Decomposition: everything except the h-recurrence is h-independent and is
// precomputed in parallel kernels; the scan kernel keeps R in registers
// (393 KB bf16, 1 block/CU at 1 wave/SIMD) and h in LDS.
// ---------------------------------------------------------------------------

#define Bsz 256
#define Tsz 512
#define Dsz 128
#define Hsz 256
#define BT  (Bsz * Tsz)          // 131072
#define N3H 768                  // 3*H

typedef __attribute__((ext_vector_type(8))) short   short8;
typedef __attribute__((ext_vector_type(8))) __bf16  bf16x8;
typedef __attribute__((ext_vector_type(4))) float   f32x4;

__device__ __forceinline__ unsigned short f2bf(float f) {
    union { float f; unsigned u; } v; v.f = f;
    unsigned r = v.u + 0x7fffu + ((v.u >> 16) & 1u);   // RNE
    return (unsigned short)(r >> 16);
}
__device__ __forceinline__ float b2f(unsigned short u) {
    union { unsigned u; float f; } v; v.u = ((unsigned)u) << 16;
    return v.f;
}
__device__ __forceinline__ bf16x8 ld_frag(const unsigned short* p) {
    short8 v = *(const short8*)p;
    return __builtin_bit_cast(bf16x8, v);
}

// ---------------------------------------------------------------------------
// K0: transpose+convert weights to bf16, N-major (so MFMA B-frag reads are
// contiguous 16B): KM_T[768][256] = [kernel;masking]^T, R_T[768][256],
// W_T[256][128] = hidden_decay_kernel^T.
// ---------------------------------------------------------------------------
__global__ void k_pack(const float* __restrict__ kern, const float* __restrict__ maskk,
                       const float* __restrict__ rk,   const float* __restrict__ hdk,
                       unsigned short* __restrict__ KM_T, unsigned short* __restrict__ R_T,
                       unsigned short* __restrict__ W_T) {
    int i = blockIdx.x * 256 + threadIdx.x;
    if (i < N3H * 256) {
        int n = i >> 8, k = i & 255;
        float v = (k < 128) ? kern[k * N3H + n] : maskk[(k - 128) * N3H + n];
        KM_T[i] = f2bf(v);
        R_T[i]  = f2bf(rk[k * N3H + n]);
    } else {
        int j = i - N3H * 256;
        if (j < 256 * 128) {
            int n = j >> 7, k = j & 127;
            W_T[j] = f2bf(hdk[k * 256 + n]);
        }
    }
}

// ---------------------------------------------------------------------------
// K1: LOCF scan, one thread per (b,d). Emits X2 (B,T,256) = [x_eff | mf] bf16
// and Dt (B,T,128) = (s_t - s_prev) bf16.
// ---------------------------------------------------------------------------
__global__ __launch_bounds__(256) void k_locf(
        const float* __restrict__ x, const int* __restrict__ m,
        const float* __restrict__ s, const float* __restrict__ wdi,
        const float* __restrict__ bdi,
        unsigned short* __restrict__ X2, unsigned short* __restrict__ Dt) {
    int gid = blockIdx.x * blockDim.x + threadIdx.x;   // 32768
    int b = gid >> 7, d = gid & 127;
    float w  = wdi[d], bi = bdi[d];
    float x_keep = 0.f, s_prev = 0.f;
    const float* xb  = x + (size_t)b * Tsz * Dsz + d;
    const int*   mb_ = m + (size_t)b * Tsz * Dsz + d;
    const float* sb  = s + (size_t)b * Tsz;
    unsigned short* X2b = X2 + (size_t)b * Tsz * 256 + d;
    unsigned short* Dtb = Dt + (size_t)b * Tsz * 128 + d;
    for (int t0 = 0; t0 < Tsz; t0 += 4) {
        float xv[4], sv[4]; int mv[4];
#pragma unroll
        for (int u = 0; u < 4; u++) {
            xv[u] = xb[(size_t)(t0 + u) * Dsz];
            mv[u] = mb_[(size_t)(t0 + u) * Dsz];
            sv[u] = sb[t0 + u];
        }
#pragma unroll
        for (int u = 0; u < 4; u++) {
            int t = t0 + u;
            float dt  = sv[u] - s_prev;
            float gdi = __expf(-fmaxf(dt * w + bi, 0.f));
            bool  mbt = mv[u] > 0;
            if (mbt) x_keep = xv[u];
            float xe = mbt ? xv[u] : gdi * x_keep;
            if (mbt) s_prev = sv[u];
            X2b[(size_t)t * 256]       = f2bf(xe);
            X2b[(size_t)t * 256 + 128] = f2bf((float)mv[u]);
            Dtb[(size_t)t * 128]       = f2bf(dt);
        }
    }
}

// ---------------------------------------------------------------------------
// K2: bf16 MFMA GEMM, 128x128 tile, BK=32, 4 waves (2x2 of 64x64).
// A (M x K) row-major bf16, Bt (N x K) row-major bf16 (i.e. B transposed).
// MODE 0: C = A@B + bias ; MODE 1: C = exp(-relu(A@B + bias)). C bf16.
// ---------------------------------------------------------------------------
template <int MODE, int K, int N>
__global__ __launch_bounds__(256) void k_gemm(
        const unsigned short* __restrict__ A, const unsigned short* __restrict__ Bt,
        const float* __restrict__ bias, unsigned short* __restrict__ C) {
    __shared__ unsigned short As[128][40];
    __shared__ unsigned short Bs[128][40];
    int m0 = blockIdx.x * 128, n0 = blockIdx.y * 128;
    int tid = threadIdx.x, lane = tid & 63, w = tid >> 6;
    int wm = w & 1, wn = w >> 1;
    int r15 = lane & 15, q = lane >> 4;
    int arow = tid >> 2, akg = tid & 3;
    f32x4 acc[4][4];
#pragma unroll
    for (int i = 0; i < 4; i++)
#pragma unroll
        for (int j = 0; j < 4; j++) acc[i][j] = f32x4{0.f, 0.f, 0.f, 0.f};

    for (int kk = 0; kk < K; kk += 32) {
        short8 av0 = *(const short8*)(A  + (size_t)(m0 + arow)      * K + kk + akg * 8);
        short8 av1 = *(const short8*)(A  + (size_t)(m0 + arow + 64) * K + kk + akg * 8);
        short8 bv0 = *(const short8*)(Bt + (size_t)(n0 + arow)      * K + kk + akg * 8);
        short8 bv1 = *(const short8*)(Bt + (size_t)(n0 + arow + 64) * K + kk + akg * 8);
        *(short8*)&As[arow][akg * 8]      = av0;
        *(short8*)&As[arow + 64][akg * 8] = av1;
        *(short8*)&Bs[arow][akg * 8]      = bv0;
        *(short8*)&Bs[arow + 64][akg * 8] = bv1;
        __syncthreads();
        bf16x8 af[4], bf[4];
#pragma unroll
        for (int i = 0; i < 4; i++) af[i] = ld_frag(&As[wm * 64 + i * 16 + r15][q * 8]);
#pragma unroll
        for (int j = 0; j < 4; j++) bf[j] = ld_frag(&Bs[wn * 64 + j * 16 + r15][q * 8]);
#pragma unroll
        for (int i = 0; i < 4; i++)
#pragma unroll
            for (int j = 0; j < 4; j++)
                acc[i][j] = __builtin_amdgcn_mfma_f32_16x16x32_bf16(af[i], bf[j], acc[i][j], 0, 0, 0);
        __syncthreads();
    }
#pragma unroll
    for (int i = 0; i < 4; i++)
#pragma unroll
        for (int j = 0; j < 4; j++) {
            int col = n0 + wn * 64 + j * 16 + r15;
            float bs = bias[col];
#pragma unroll
            for (int rg = 0; rg < 4; rg++) {
                int row = m0 + wm * 64 + i * 16 + q * 4 + rg;
                float v = acc[i][j][rg] + bs;
                if (MODE == 1) v = __expf(-fmaxf(v, 0.f));
                C[(size_t)row * N + col] = f2bf(v);
            }
        }
}

// ---------------------------------------------------------------------------
// K3: recurrent scan. 256 blocks (one per batch element), 4 waves.
// Wave w holds B-frags for R_zr cols [w*128, w*128+128) and Rh cols
// [512+w*64, 512+w*64+64) in registers (384 VGPRs). h in LDS (fp32).
// A-operand = h_d (or u) broadcast to all 16 MFMA rows -> all output rows
// identical -> lane L holds result for col (L&15) of its tile.
// ---------------------------------------------------------------------------
__global__ __launch_bounds__(256, 1) void k_scan(
        const unsigned short* __restrict__ Apre, const unsigned short* __restrict__ G,
        const unsigned short* __restrict__ R_T, float* __restrict__ out) {
    int b = blockIdx.x;
    int tid = threadIdx.x, lane = tid & 63, w = tid >> 6;
    int r15 = lane & 15, q = lane >> 4;

    __shared__ float h_lds[256];
    __shared__ float z_buf[256];
    __shared__ __align__(16) unsigned short hd_bf[256];
    __shared__ __align__(16) unsigned short u_bf[256];
    __shared__ __align__(16) unsigned short ap_l[2][768];
    __shared__ __align__(16) unsigned short g_l[2][256];

    // persistent weight fragments
    bf16x8 fzr[8][8];   // zr cols: w*128 + nt*16 + r15
    bf16x8 fh[4][8];    // hh cols: 512 + w*64 + nt*16 + r15
#pragma unroll
    for (int nt = 0; nt < 8; nt++) {
        const unsigned short* base = R_T + (size_t)(w * 128 + nt * 16 + r15) * 256 + q * 8;
#pragma unroll
        for (int kt = 0; kt < 8; kt++) fzr[nt][kt] = ld_frag(base + kt * 32);
    }
#pragma unroll
    for (int nt = 0; nt < 4; nt++) {
        const unsigned short* base = R_T + (size_t)(512 + w * 64 + nt * 16 + r15) * 256 + q * 8;
#pragma unroll
        for (int kt = 0; kt < 8; kt++) fh[nt][kt] = ld_frag(base + kt * 32);
    }

    h_lds[tid] = 0.f;
    const unsigned short* aprow = Apre + (size_t)b * Tsz * N3H;
    const unsigned short* grow  = G    + (size_t)b * Tsz * 256;
    // preload t=0 into LDS buf0, t=1 into regs
    uint2 pfA;
    if (tid < 192) {
        *(uint2*)&ap_l[0][tid * 4] = *(const uint2*)(aprow + tid * 4);
        pfA = *(const uint2*)(aprow + N3H + tid * 4);
    } else {
        int t2 = tid - 192;
        *(uint2*)&g_l[0][t2 * 4] = *(const uint2*)(grow + t2 * 4);
        pfA = *(const uint2*)(grow + 256 + t2 * 4);
    }
    __syncthreads();

    float* outb = out + (size_t)b * Tsz * 256;
    for (int t = 0; t < Tsz; t++) {
        int buf = t & 1;
        int tp2 = (t + 2 < Tsz) ? t + 2 : Tsz - 1;
        uint2 pfB;
        if (tid < 192) pfB = *(const uint2*)(aprow + (size_t)tp2 * N3H + tid * 4);
        else           pfB = *(const uint2*)(grow  + (size_t)tp2 * 256 + (tid - 192) * 4);

        // phase 1: h_d = G_t * h
        {
            float hd = b2f(g_l[buf][tid]) * h_lds[tid];
            hd_bf[tid] = f2bf(hd);
        }
        __syncthreads();

        // phase 2: zr = Apre[:512] + h_d @ R_zr
        f32x4 acc[8];
#pragma unroll
        for (int nt = 0; nt < 8; nt++) acc[nt] = f32x4{0.f, 0.f, 0.f, 0.f};
#pragma unroll
        for (int kt = 0; kt < 8; kt++) {
            bf16x8 afr = ld_frag(&hd_bf[kt * 32 + q * 8]);   // lane-uniform per quad
#pragma unroll
            for (int nt = 0; nt < 8; nt++)
                acc[nt] = __builtin_amdgcn_mfma_f32_16x16x32_bf16(afr, fzr[nt][kt], acc[nt], 0, 0, 0);
        }
#pragma unroll
        for (int nt = 0; nt < 8; nt++) {
            int c = w * 128 + nt * 16 + r15;
            float pre = acc[nt][0] + b2f(ap_l[buf][c]);
            if (w < 2) {                         // z columns 0..255
                if (lane < 16) z_buf[c] = 1.f / (1.f + __expf(-pre));
            } else {                             // r columns 256..511 -> u
                int uc = c - 256;
                if (lane < 16) {
                    float hd = b2f(g_l[buf][uc]) * h_lds[uc];
                    u_bf[uc] = f2bf(pre * hd);
                }
            }
        }
        __syncthreads();

        // phase 3: hh = tanh(Apre[512:] + u @ Rh); h update
        f32x4 acch[4];
#pragma unroll
        for (int nt = 0; nt < 4; nt++) acch[nt] = f32x4{0.f, 0.f, 0.f, 0.f};
#pragma unroll
        for (int kt = 0; kt < 8; kt++) {
            bf16x8 afr = ld_frag(&u_bf[kt * 32 + q * 8]);
#pragma unroll
            for (int nt = 0; nt < 4; nt++)
                acch[nt] = __builtin_amdgcn_mfma_f32_16x16x32_bf16(afr, fh[nt][kt], acch[nt], 0, 0, 0);
        }
#pragma unroll
        for (int nt = 0; nt < 4; nt++) {
            int ch = w * 64 + nt * 16 + r15;
            float pre = acch[nt][0] + b2f(ap_l[buf][512 + ch]);
            if (lane < 16) {
                float e2 = __expf(2.f * pre);
                float hh = 1.f - 2.f / (e2 + 1.f);          // tanh, inf-safe
                float z  = z_buf[ch];
                float hn = z * h_lds[ch] + (1.f - z) * hh;
                h_lds[ch] = hn;
                outb[(size_t)t * 256 + ch] = hn;
            }
        }
        // write prefetched t+1 row into the other buffer
        if (tid < 192) *(uint2*)&ap_l[buf ^ 1][tid * 4] = pfA;
        else           *(uint2*)&g_l[buf ^ 1][(tid - 192) * 4] = pfA;
        pfA = pfB;
        __syncthreads();
    }
}

// ---------------------------------------------------------------------------
extern "C" void kernel_launch(void* const* d_in, const int* in_sizes, int n_in,
                              void* d_out, int out_size, void* d_ws, size_t ws_size,
                              hipStream_t stream) {
    const float* x    = (const float*)d_in[0];
    const int*   m    = (const int*)  d_in[1];
    const float* s    = (const float*)d_in[2];
    const float* kern = (const float*)d_in[3];
    const float* rk   = (const float*)d_in[4];
    const float* mk   = (const float*)d_in[5];
    const float* bias = (const float*)d_in[6];
    const float* wdi  = (const float*)d_in[7];
    const float* bdi  = (const float*)d_in[8];
    const float* hdk  = (const float*)d_in[9];
    const float* hdb  = (const float*)d_in[10];
    float* out = (float*)d_out;

    char* ws = (char*)d_ws;
    size_t off = 0;
    auto alloc = [&](size_t bytes) -> void* {
        void* p = ws + off; off += (bytes + 255) & ~(size_t)255; return p;
    };
    unsigned short* X2   = (unsigned short*)alloc((size_t)BT * 256 * 2); // 67 MB
    unsigned short* Dt   = (unsigned short*)alloc((size_t)BT * 128 * 2); // 33.6 MB
    unsigned short* Apre = (unsigned short*)alloc((size_t)BT * N3H * 2); // 201 MB
    unsigned short* Gm   = (unsigned short*)alloc((size_t)BT * 256 * 2); // 67 MB
    unsigned short* KM_T = (unsigned short*)alloc((size_t)N3H * 256 * 2);
    unsigned short* R_T  = (unsigned short*)alloc((size_t)N3H * 256 * 2);
    unsigned short* W_T  = (unsigned short*)alloc((size_t)256 * 128 * 2);
    (void)ws_size; (void)in_sizes; (void)n_in; (void)out_size;

    // pack/transpose weights to bf16
    k_pack<<<dim3((N3H * 256 + 256 * 128 + 255) / 256), dim3(256), 0, stream>>>(
        kern, mk, rk, hdk, KM_T, R_T, W_T);
    // LOCF scan -> X2, Dt
    k_locf<<<dim3(Bsz * Dsz / 256), dim3(256), 0, stream>>>(x, m, s, wdi, bdi, X2, Dt);
    // Apre = X2 @ [K;M] + bias
    k_gemm<0, 256, N3H><<<dim3(BT / 128, N3H / 128), dim3(256), 0, stream>>>(X2, KM_T, bias, Apre);
    // G = exp(-relu(Dt @ Wdh + bdh))
    k_gemm<1, 128, 256><<<dim3(BT / 128, 256 / 128), dim3(256), 0, stream>>>(Dt, W_T, hdb, Gm);
    // recurrent scan
    k_scan<<<dim3(Bsz), dim3(256), 0, stream>>>(Apre, Gm, R_T, out);
}

// Round 2
// 1115.806 us; speedup vs baseline: 1.6901x; 1.6901x over previous
//
#include <hip/hip_runtime.h>
#include <hip/hip_bf16.h>
#include <cstdint>

// ---------------------------------------------------------------------------
// GRU-D: B=256, T=512, D=128, H=256.
// x-path (LOCF, input decay, mask proj, all GEMMs vs inputs) is h-independent
// and precomputed in parallel; the recurrent scan keeps R in registers spread
// across 8 waves (48 frags = 192 VGPRs/wave, pinned vs rematerialization).
// ---------------------------------------------------------------------------

#define Bsz 256
#define Tsz 512
#define Dsz 128
#define Hsz 256
#define BT  (Bsz * Tsz)          // 131072
#define N3H 768                  // 3*H

typedef __attribute__((ext_vector_type(8))) short   short8;
typedef __attribute__((ext_vector_type(8))) __bf16  bf16x8;
typedef __attribute__((ext_vector_type(4))) float   f32x4;

__device__ __forceinline__ unsigned short f2bf(float f) {
    union { float f; unsigned u; } v; v.f = f;
    unsigned r = v.u + 0x7fffu + ((v.u >> 16) & 1u);   // RNE
    return (unsigned short)(r >> 16);
}
__device__ __forceinline__ float b2f(unsigned short u) {
    union { unsigned u; float f; } v; v.u = ((unsigned)u) << 16;
    return v.f;
}
__device__ __forceinline__ bf16x8 ld_frag(const unsigned short* p) {
    short8 v = *(const short8*)p;
    return __builtin_bit_cast(bf16x8, v);
}

// ---------------------------------------------------------------------------
// K0: transpose+convert weights to bf16, N-major.
// ---------------------------------------------------------------------------
__global__ void k_pack(const float* __restrict__ kern, const float* __restrict__ maskk,
                       const float* __restrict__ rk,   const float* __restrict__ hdk,
                       unsigned short* __restrict__ KM_T, unsigned short* __restrict__ R_T,
                       unsigned short* __restrict__ W_T) {
    int i = blockIdx.x * 256 + threadIdx.x;
    if (i < N3H * 256) {
        int n = i >> 8, k = i & 255;
        float v = (k < 128) ? kern[k * N3H + n] : maskk[(k - 128) * N3H + n];
        KM_T[i] = f2bf(v);
        R_T[i]  = f2bf(rk[k * N3H + n]);
    } else {
        int j = i - N3H * 256;
        if (j < 256 * 128) {
            int n = j >> 7, k = j & 127;
            W_T[j] = f2bf(hdk[k * 256 + n]);
        }
    }
}

// ---------------------------------------------------------------------------
// K1: LOCF scan, one thread per (b,d).
// ---------------------------------------------------------------------------
__global__ __launch_bounds__(256) void k_locf(
        const float* __restrict__ x, const int* __restrict__ m,
        const float* __restrict__ s, const float* __restrict__ wdi,
        const float* __restrict__ bdi,
        unsigned short* __restrict__ X2, unsigned short* __restrict__ Dt) {
    int gid = blockIdx.x * blockDim.x + threadIdx.x;   // 32768
    int b = gid >> 7, d = gid & 127;
    float w  = wdi[d], bi = bdi[d];
    float x_keep = 0.f, s_prev = 0.f;
    const float* xb  = x + (size_t)b * Tsz * Dsz + d;
    const int*   mb_ = m + (size_t)b * Tsz * Dsz + d;
    const float* sb  = s + (size_t)b * Tsz;
    unsigned short* X2b = X2 + (size_t)b * Tsz * 256 + d;
    unsigned short* Dtb = Dt + (size_t)b * Tsz * 128 + d;
    for (int t0 = 0; t0 < Tsz; t0 += 4) {
        float xv[4], sv[4]; int mv[4];
#pragma unroll
        for (int u = 0; u < 4; u++) {
            xv[u] = xb[(size_t)(t0 + u) * Dsz];
            mv[u] = mb_[(size_t)(t0 + u) * Dsz];
            sv[u] = sb[t0 + u];
        }
#pragma unroll
        for (int u = 0; u < 4; u++) {
            int t = t0 + u;
            float dt  = sv[u] - s_prev;
            float gdi = __expf(-fmaxf(dt * w + bi, 0.f));
            bool  mbt = mv[u] > 0;
            if (mbt) x_keep = xv[u];
            float xe = mbt ? xv[u] : gdi * x_keep;
            if (mbt) s_prev = sv[u];
            X2b[(size_t)t * 256]       = f2bf(xe);
            X2b[(size_t)t * 256 + 128] = f2bf((float)mv[u]);
            Dtb[(size_t)t * 128]       = f2bf(dt);
        }
    }
}

// ---------------------------------------------------------------------------
// K2: bf16 MFMA GEMM, 128x128 tile, BK=32, 4 waves (2x2 of 64x64).
// MODE 0: C = A@B + bias ; MODE 1: C = exp(-relu(A@B + bias)). C bf16.
// ---------------------------------------------------------------------------
template <int MODE, int K, int N>
__global__ __launch_bounds__(256) void k_gemm(
        const unsigned short* __restrict__ A, const unsigned short* __restrict__ Bt,
        const float* __restrict__ bias, unsigned short* __restrict__ C) {
    __shared__ unsigned short As[128][40];
    __shared__ unsigned short Bs[128][40];
    int m0 = blockIdx.x * 128, n0 = blockIdx.y * 128;
    int tid = threadIdx.x, lane = tid & 63, w = tid >> 6;
    int wm = w & 1, wn = w >> 1;
    int r15 = lane & 15, q = lane >> 4;
    int arow = tid >> 2, akg = tid & 3;
    f32x4 acc[4][4];
#pragma unroll
    for (int i = 0; i < 4; i++)
#pragma unroll
        for (int j = 0; j < 4; j++) acc[i][j] = f32x4{0.f, 0.f, 0.f, 0.f};

    for (int kk = 0; kk < K; kk += 32) {
        short8 av0 = *(const short8*)(A  + (size_t)(m0 + arow)      * K + kk + akg * 8);
        short8 av1 = *(const short8*)(A  + (size_t)(m0 + arow + 64) * K + kk + akg * 8);
        short8 bv0 = *(const short8*)(Bt + (size_t)(n0 + arow)      * K + kk + akg * 8);
        short8 bv1 = *(const short8*)(Bt + (size_t)(n0 + arow + 64) * K + kk + akg * 8);
        *(short8*)&As[arow][akg * 8]      = av0;
        *(short8*)&As[arow + 64][akg * 8] = av1;
        *(short8*)&Bs[arow][akg * 8]      = bv0;
        *(short8*)&Bs[arow + 64][akg * 8] = bv1;
        __syncthreads();
        bf16x8 af[4], bf[4];
#pragma unroll
        for (int i = 0; i < 4; i++) af[i] = ld_frag(&As[wm * 64 + i * 16 + r15][q * 8]);
#pragma unroll
        for (int j = 0; j < 4; j++) bf[j] = ld_frag(&Bs[wn * 64 + j * 16 + r15][q * 8]);
#pragma unroll
        for (int i = 0; i < 4; i++)
#pragma unroll
            for (int j = 0; j < 4; j++)
                acc[i][j] = __builtin_amdgcn_mfma_f32_16x16x32_bf16(af[i], bf[j], acc[i][j], 0, 0, 0);
        __syncthreads();
    }
#pragma unroll
    for (int i = 0; i < 4; i++)
#pragma unroll
        for (int j = 0; j < 4; j++) {
            int col = n0 + wn * 64 + j * 16 + r15;
            float bs = bias[col];
#pragma unroll
            for (int rg = 0; rg < 4; rg++) {
                int row = m0 + wm * 64 + i * 16 + q * 4 + rg;
                float v = acc[i][j][rg] + bs;
                if (MODE == 1) v = __expf(-fmaxf(v, 0.f));
                C[(size_t)row * N + col] = f2bf(v);
            }
        }
}

// ---------------------------------------------------------------------------
// K3: recurrent scan. 256 blocks (one per batch), 8 waves (512 thr).
// Wave w: zr cols [w*64, w*64+64) -> 4 tiles; hh cols [512+w*32, +32) -> 2
// tiles. 48 frags = 192 VGPRs/wave, pinned via asm so the allocator cannot
// rematerialize the global loads inside the t-loop (round-1 failure mode:
// 51.5 GB of L2 weight re-reads at the 34 TB/s L2 ceiling).
// A-operand is the h_d vector broadcast to all 16 rows -> every lane holds
// the result for col (lane&15) of each tile in acc[*][0].
// 2 barriers/step: h_d for step t+1 is produced in step t's phase-3 epilogue
// using the prefetched G row.
// ---------------------------------------------------------------------------
__global__ __launch_bounds__(512, 2) void k_scan(
        const unsigned short* __restrict__ Apre, const unsigned short* __restrict__ G,
        const unsigned short* __restrict__ R_T, float* __restrict__ out) {
    int b = blockIdx.x;
    int tid = threadIdx.x, lane = tid & 63, w = tid >> 6;
    int r15 = lane & 15, q = lane >> 4;

    __shared__ float h_lds[256];
    __shared__ float hd_f32[256];
    __shared__ float z_buf[256];
    __shared__ __align__(16) unsigned short hd_bf[256];
    __shared__ __align__(16) unsigned short u_bf[256];
    __shared__ __align__(16) unsigned short ap_l[2][768];
    __shared__ __align__(16) unsigned short g_l[2][256];

    // ---- persistent weight fragments (192 VGPRs/wave) ----
    bf16x8 fzr[4][8];   // zr cols: w*64 + nt*16 + r15
    bf16x8 fh[2][8];    // hh cols: 512 + w*32 + nt*16 + r15
#pragma unroll
    for (int nt = 0; nt < 4; nt++) {
        const unsigned short* base = R_T + (size_t)(w * 64 + nt * 16 + r15) * 256 + q * 8;
#pragma unroll
        for (int kt = 0; kt < 8; kt++) {
            fzr[nt][kt] = ld_frag(base + kt * 32);
            asm volatile("" : "+v"(fzr[nt][kt]));   // pin: no remat in loop
        }
    }
#pragma unroll
    for (int nt = 0; nt < 2; nt++) {
        const unsigned short* base = R_T + (size_t)(512 + w * 32 + nt * 16 + r15) * 256 + q * 8;
#pragma unroll
        for (int kt = 0; kt < 8; kt++) {
            fh[nt][kt] = ld_frag(base + kt * 32);
            asm volatile("" : "+v"(fh[nt][kt]));
        }
    }

    if (tid < 256) { h_lds[tid] = 0.f; hd_f32[tid] = 0.f; hd_bf[tid] = 0; }

    const unsigned short* aprow = Apre + (size_t)b * Tsz * N3H;
    const unsigned short* grow  = G    + (size_t)b * Tsz * 256;

    // preload t=0 and t=1 rows (ap: 768 each, g: 256 each), uint2 = 4 ushorts
    if (tid < 192)      *(uint2*)&ap_l[0][tid * 4]         = *(const uint2*)(aprow + tid * 4);
    else if (tid < 384) *(uint2*)&ap_l[1][(tid-192) * 4]   = *(const uint2*)(aprow + N3H + (tid-192) * 4);
    else if (tid < 448) *(uint2*)&g_l[0][(tid-384) * 4]    = *(const uint2*)(grow + (tid-384) * 4);
    else                *(uint2*)&g_l[1][(tid-448) * 4]    = *(const uint2*)(grow + 256 + (tid-448) * 4);
    __syncthreads();

    float* outb = out + (size_t)b * Tsz * 256;
    for (int t = 0; t < Tsz; t++) {
        int buf = t & 1;
        int tp2 = (t + 2 < Tsz) ? t + 2 : Tsz - 1;
        // prefetch row t+2 into a register (1 VGPR/thread)
        unsigned pf;
        if (tid < 384) pf = *(const unsigned*)(aprow + (size_t)tp2 * N3H + tid * 2);
        else           pf = *(const unsigned*)(grow  + (size_t)tp2 * 256 + (tid - 384) * 2);

        // ---- phase 2: zr = Apre[:512] + h_d @ R_zr ----
        f32x4 acc[4];
#pragma unroll
        for (int nt = 0; nt < 4; nt++) acc[nt] = f32x4{0.f, 0.f, 0.f, 0.f};
#pragma unroll
        for (int kt = 0; kt < 8; kt++) {
            bf16x8 afr = ld_frag(&hd_bf[kt * 32 + q * 8]);   // quad-uniform broadcast
#pragma unroll
            for (int nt = 0; nt < 4; nt++)
                acc[nt] = __builtin_amdgcn_mfma_f32_16x16x32_bf16(afr, fzr[nt][kt], acc[nt], 0, 0, 0);
        }
        // epilogue: quad q handles tile q (all 64 lanes active)
        {
            int c = w * 64 + q * 16 + r15;
            float pre = acc[q][0] + b2f(ap_l[buf][c]);
            if (w < 4) {                         // z columns 0..255
                z_buf[c] = 1.f / (1.f + __expf(-pre));
            } else {                             // r columns 256..511 -> u
                int uc = c - 256;
                u_bf[uc] = f2bf(pre * hd_f32[uc]);
            }
        }
        __syncthreads();

        // ---- phase 3: hh = tanh(Apre[512:] + u @ Rh); h update ----
        f32x4 acch[2];
#pragma unroll
        for (int nt = 0; nt < 2; nt++) acch[nt] = f32x4{0.f, 0.f, 0.f, 0.f};
#pragma unroll
        for (int kt = 0; kt < 8; kt++) {
            bf16x8 afr = ld_frag(&u_bf[kt * 32 + q * 8]);
#pragma unroll
            for (int nt = 0; nt < 2; nt++)
                acch[nt] = __builtin_amdgcn_mfma_f32_16x16x32_bf16(afr, fh[nt][kt], acch[nt], 0, 0, 0);
        }
        // epilogue: lanes 0..31, quad q in {0,1} handles tile q; also produce
        // h_d for step t+1 from the prefetched G row.
        if (lane < 32) {
            int ch = w * 32 + q * 16 + r15;
            float pre = acch[q][0] + b2f(ap_l[buf][512 + ch]);
            float e2 = __expf(2.f * pre);
            float hh = 1.f - 2.f / (e2 + 1.f);          // tanh, inf-safe
            float z  = z_buf[ch];
            float hn = z * h_lds[ch] + (1.f - z) * hh;
            h_lds[ch] = hn;
            outb[(size_t)t * 256 + ch] = hn;
            float hdn = b2f(g_l[buf ^ 1][ch]) * hn;     // G_{t+1} * h_t
            hd_f32[ch] = hdn;
            hd_bf[ch]  = f2bf(hdn);
        }
        __syncthreads();

        // stash prefetched t+2 row into buf (t's data is dead now); the next
        // iteration's first barrier orders these writes before any consumer.
        if (tid < 384) *(unsigned*)&ap_l[buf][tid * 2] = pf;
        else           *(unsigned*)&g_l[buf][(tid - 384) * 2] = pf;
    }
}

// ---------------------------------------------------------------------------
extern "C" void kernel_launch(void* const* d_in, const int* in_sizes, int n_in,
                              void* d_out, int out_size, void* d_ws, size_t ws_size,
                              hipStream_t stream) {
    const float* x    = (const float*)d_in[0];
    const int*   m    = (const int*)  d_in[1];
    const float* s    = (const float*)d_in[2];
    const float* kern = (const float*)d_in[3];
    const float* rk   = (const float*)d_in[4];
    const float* mk   = (const float*)d_in[5];
    const float* bias = (const float*)d_in[6];
    const float* wdi  = (const float*)d_in[7];
    const float* bdi  = (const float*)d_in[8];
    const float* hdk  = (const float*)d_in[9];
    const float* hdb  = (const float*)d_in[10];
    float* out = (float*)d_out;

    char* ws = (char*)d_ws;
    size_t off = 0;
    auto alloc = [&](size_t bytes) -> void* {
        void* p = ws + off; off += (bytes + 255) & ~(size_t)255; return p;
    };
    unsigned short* X2   = (unsigned short*)alloc((size_t)BT * 256 * 2); // 67 MB
    unsigned short* Dt   = (unsigned short*)alloc((size_t)BT * 128 * 2); // 33.6 MB
    unsigned short* Apre = (unsigned short*)alloc((size_t)BT * N3H * 2); // 201 MB
    unsigned short* Gm   = (unsigned short*)alloc((size_t)BT * 256 * 2); // 67 MB
    unsigned short* KM_T = (unsigned short*)alloc((size_t)N3H * 256 * 2);
    unsigned short* R_T  = (unsigned short*)alloc((size_t)N3H * 256 * 2);
    unsigned short* W_T  = (unsigned short*)alloc((size_t)256 * 128 * 2);
    (void)ws_size; (void)in_sizes; (void)n_in; (void)out_size;

    k_pack<<<dim3((N3H * 256 + 256 * 128 + 255) / 256), dim3(256), 0, stream>>>(
        kern, mk, rk, hdk, KM_T, R_T, W_T);
    k_locf<<<dim3(Bsz * Dsz / 256), dim3(256), 0, stream>>>(x, m, s, wdi, bdi, X2, Dt);
    k_gemm<0, 256, N3H><<<dim3(BT / 128, N3H / 128), dim3(256), 0, stream>>>(X2, KM_T, bias, Apre);
    k_gemm<1, 128, 256><<<dim3(BT / 128, 256 / 128), dim3(256), 0, stream>>>(Dt, W_T, hdb, Gm);
    k_scan<<<dim3(Bsz), dim3(512), 0, stream>>>(Apre, Gm, R_T, out);
}